// Round 2
// baseline (618.071 us; speedup 1.0000x reference)
//
#include <hip/hip_runtime.h>
#include <hip/hip_cooperative_groups.h>
#include <math.h>

namespace cg = cooperative_groups;

// EdgeFocusedGraphNetwork — collapsed algebra (validated round 1):
// fe stays rank-structured P[b,i]+Q[b,j]+r; softmax over i cancels Q,r and
// b_fe/b_ue/b_attn. Additional folds this round:
//   W_sa = W_attn @ W_ue  (precomputed once)  ->  S_t = [A_t|P_t] @ W_sa.T
//   P_0 == A_0            (reference reuses fv0 in outer_linear)
// Whole net = ~15 small GEMMs in ONE cooperative kernel with 10 grid syncs.
//
// Stages (t = 0..2):
//   s0 : fv0 = feat@W_inp.T+b_inp  ||  W_sa = W_attn@W_ue
//   s1 : A0 = fv0@W_fe1.T (dual-write both CA0 halves)  ||  xhid0
//   s2+3t : strips: S_t=[CA_t]@W_sa.T -> softmax_i -> agg -> XC[:,H:]
//           || P'_t=[CA_t]@W_ue.T -> CA_{t+1} P-half   (skipped at t=2)
//   s3+3t : fv_{t+1} = XC@W_uv.T + b_uv
//   s4+3t : A_{t+1}->CA_{t+1} A-half || xhid_{t+1}   (t=2: out = fv3@W_oup.T+b_oup)

#define H     256
#define H2    512
#define NINP  512
#define LDIM  128
#define MROWS 1024
#define NBLK  256
#define NSTAGE 11

struct NetArgs {
    const float *feat, *mask;
    const float *W_inp, *b_inp, *W_oup, *b_oup;
    const float *W_fe, *W_ue, *W_agg, *b_agg, *W_uv, *b_uv, *W_attn;
    float *out, *fvA, *fvB, *ca0, *ca1, *xc, *wsa;
};

// ---- 32x32 output tile GEMM: Y = (X*rowscale) @ W(.T) + bias --------------
// LDS transposed tiles: Xt[kk][m] stride 36, Wt[kk][n] stride 36 -> inner
// loop is 2x ds_read_b64 per kk, conflict-free (scatter stores are <=4-way,
// amortized over 32 kk iterations).
__device__ __forceinline__ void tile32(
    const float* __restrict__ X, int ldx,
    const float* __restrict__ W, int ldw, int wNN,
    const float* __restrict__ bias, const float* __restrict__ rowscale,
    float* __restrict__ Y, float* __restrict__ Y2, int ldy,
    int K, int bm, int bn, int tid, float* lds)
{
    float* Xt = lds;            // [32][36]
    float* Wt = lds + 1152;     // [32][36]
    const int lr = tid >> 3;          // 0..31
    const int lc = (tid & 7) << 2;    // 0,4,..,28
    const int ty = tid >> 4;          // 0..15
    const int tx = tid & 15;          // 0..15
    const float rsc = rowscale ? rowscale[bm + lr] : 1.0f;
    const float* xp = X + (size_t)(bm + lr) * ldx + lc;

    float a00 = 0.f, a01 = 0.f, a10 = 0.f, a11 = 0.f;

    for (int k0 = 0; k0 < K; k0 += 32) {
        float4 xv = *(const float4*)(xp + k0);
        float4 wv;
        if (wNN) wv = *(const float4*)(W + (size_t)(k0 + lr) * ldw + bn + lc);
        else     wv = *(const float4*)(W + (size_t)(bn + lr) * ldw + k0 + lc);
        __syncthreads();
        Xt[(lc + 0) * 36 + lr] = xv.x * rsc;
        Xt[(lc + 1) * 36 + lr] = xv.y * rsc;
        Xt[(lc + 2) * 36 + lr] = xv.z * rsc;
        Xt[(lc + 3) * 36 + lr] = xv.w * rsc;
        if (wNN) {
            *(float4*)(Wt + lr * 36 + lc) = wv;   // rows are already kk
        } else {
            Wt[(lc + 0) * 36 + lr] = wv.x;
            Wt[(lc + 1) * 36 + lr] = wv.y;
            Wt[(lc + 2) * 36 + lr] = wv.z;
            Wt[(lc + 3) * 36 + lr] = wv.w;
        }
        __syncthreads();
        #pragma unroll
        for (int kk = 0; kk < 32; ++kk) {
            float2 x2 = *(const float2*)(Xt + kk * 36 + 2 * ty);
            float2 w2 = *(const float2*)(Wt + kk * 36 + 2 * tx);
            a00 = fmaf(x2.x, w2.x, a00);
            a01 = fmaf(x2.x, w2.y, a01);
            a10 = fmaf(x2.y, w2.x, a10);
            a11 = fmaf(x2.y, w2.y, a11);
        }
    }
    const float b0 = bias ? bias[bn + 2 * tx]     : 0.f;
    const float b1 = bias ? bias[bn + 2 * tx + 1] : 0.f;
    float* y = Y + (size_t)(bm + 2 * ty) * ldy + bn + 2 * tx;
    y[0] = a00 + b0; y[1] = a01 + b1; y[ldy] = a10 + b0; y[ldy + 1] = a11 + b1;
    if (Y2) {
        float* z = Y2 + (size_t)(bm + 2 * ty) * ldy + bn + 2 * tx;
        z[0] = a00 + b0; z[1] = a01 + b1; z[ldy] = a10 + b0; z[ldy + 1] = a11 + b1;
    }
}

// ---- S-strip: 128(i) x 32(h) tile of S = CA@W_sa.T, K=512, then in-block
// two-pass softmax over i, weighted by xhid, sigmoid, broadcast-write agg. --
__device__ __forceinline__ void strip_softmax(
    const float* __restrict__ CA,   // (1024,512)
    const float* __restrict__ Wsa,  // (256,512)
    float* __restrict__ XC,         // [:, :H]=xhid (r), [:, H:]=agg (w)
    int sid, int tid, float* lds)
{
    const int b  = sid >> 3;
    const int hs = (sid & 7) << 5;
    float* Xt = lds;            // [32][132] : Xt[kk][i]
    float* Wt = lds + 4224;     // [32][36]
    const int lr = tid >> 3;
    const int lc = (tid & 7) << 2;
    const int ty = tid >> 4;          // i-group (8 rows each)
    const int tx = tid & 15;          // h-pair
    const float* Xbase = CA + (size_t)(b * LDIM) * H2;

    float acc[8][2];
    #pragma unroll
    for (int i = 0; i < 8; ++i) { acc[i][0] = 0.f; acc[i][1] = 0.f; }

    for (int k0 = 0; k0 < H2; k0 += 32) {
        float4 xv0 = *(const float4*)(Xbase + (size_t)(lr +  0) * H2 + k0 + lc);
        float4 xv1 = *(const float4*)(Xbase + (size_t)(lr + 32) * H2 + k0 + lc);
        float4 xv2 = *(const float4*)(Xbase + (size_t)(lr + 64) * H2 + k0 + lc);
        float4 xv3 = *(const float4*)(Xbase + (size_t)(lr + 96) * H2 + k0 + lc);
        float4 wv  = *(const float4*)(Wsa + (size_t)(hs + lr) * H2 + k0 + lc);
        __syncthreads();
        #pragma unroll
        for (int c = 0; c < 4; ++c) {
            float x0 = c == 0 ? xv0.x : c == 1 ? xv0.y : c == 2 ? xv0.z : xv0.w;
            float x1 = c == 0 ? xv1.x : c == 1 ? xv1.y : c == 2 ? xv1.z : xv1.w;
            float x2 = c == 0 ? xv2.x : c == 1 ? xv2.y : c == 2 ? xv2.z : xv2.w;
            float x3 = c == 0 ? xv3.x : c == 1 ? xv3.y : c == 2 ? xv3.z : xv3.w;
            float w  = c == 0 ? wv.x  : c == 1 ? wv.y  : c == 2 ? wv.z  : wv.w;
            Xt[(lc + c) * 132 + lr +  0] = x0;
            Xt[(lc + c) * 132 + lr + 32] = x1;
            Xt[(lc + c) * 132 + lr + 64] = x2;
            Xt[(lc + c) * 132 + lr + 96] = x3;
            Wt[(lc + c) * 36 + lr] = w;
        }
        __syncthreads();
        #pragma unroll
        for (int kk = 0; kk < 32; ++kk) {
            float4 xa = *(const float4*)(Xt + kk * 132 + 8 * ty);
            float4 xb = *(const float4*)(Xt + kk * 132 + 8 * ty + 4);
            float2 w2 = *(const float2*)(Wt + kk * 36 + 2 * tx);
            acc[0][0] = fmaf(xa.x, w2.x, acc[0][0]); acc[0][1] = fmaf(xa.x, w2.y, acc[0][1]);
            acc[1][0] = fmaf(xa.y, w2.x, acc[1][0]); acc[1][1] = fmaf(xa.y, w2.y, acc[1][1]);
            acc[2][0] = fmaf(xa.z, w2.x, acc[2][0]); acc[2][1] = fmaf(xa.z, w2.y, acc[2][1]);
            acc[3][0] = fmaf(xa.w, w2.x, acc[3][0]); acc[3][1] = fmaf(xa.w, w2.y, acc[3][1]);
            acc[4][0] = fmaf(xb.x, w2.x, acc[4][0]); acc[4][1] = fmaf(xb.x, w2.y, acc[4][1]);
            acc[5][0] = fmaf(xb.y, w2.x, acc[5][0]); acc[5][1] = fmaf(xb.y, w2.y, acc[5][1]);
            acc[6][0] = fmaf(xb.z, w2.x, acc[6][0]); acc[6][1] = fmaf(xb.z, w2.y, acc[6][1]);
            acc[7][0] = fmaf(xb.w, w2.x, acc[7][0]); acc[7][1] = fmaf(xb.w, w2.y, acc[7][1]);
        }
    }
    // ---- softmax over i (two-pass, exact), weighted by xhid, sigmoid ----
    __syncthreads();                    // done reading Xt; reuse as reduction buf
    float* red_m = lds;                 // [16][34]
    float* red_s = lds + 544;
    float* red_a = lds + 1088;

    float m0 = acc[0][0], m1 = acc[0][1];
    #pragma unroll
    for (int i = 1; i < 8; ++i) { m0 = fmaxf(m0, acc[i][0]); m1 = fmaxf(m1, acc[i][1]); }
    red_m[ty * 34 + 2 * tx] = m0;
    red_m[ty * 34 + 2 * tx + 1] = m1;
    __syncthreads();
    float M0 = -3.402823466e38f, M1 = -3.402823466e38f;
    #pragma unroll
    for (int r = 0; r < 16; ++r) {
        M0 = fmaxf(M0, red_m[r * 34 + 2 * tx]);
        M1 = fmaxf(M1, red_m[r * 34 + 2 * tx + 1]);
    }
    const float* xh = XC + (size_t)(b * LDIM) * H2 + hs + 2 * tx;
    float s0 = 0.f, s1 = 0.f, a0 = 0.f, a1 = 0.f;
    #pragma unroll
    for (int i = 0; i < 8; ++i) {
        float2 x2 = *(const float2*)(xh + (size_t)(ty * 8 + i) * H2);
        float e0 = expf(acc[i][0] - M0);
        float e1 = expf(acc[i][1] - M1);
        s0 += e0; s1 += e1;
        a0 = fmaf(e0, x2.x, a0); a1 = fmaf(e1, x2.y, a1);
    }
    red_s[ty * 34 + 2 * tx] = s0; red_s[ty * 34 + 2 * tx + 1] = s1;
    red_a[ty * 34 + 2 * tx] = a0; red_a[ty * 34 + 2 * tx + 1] = a1;
    __syncthreads();
    float S0 = 0.f, S1 = 0.f, A0 = 0.f, A1 = 0.f;
    #pragma unroll
    for (int r = 0; r < 16; ++r) {
        S0 += red_s[r * 34 + 2 * tx]; S1 += red_s[r * 34 + 2 * tx + 1];
        A0 += red_a[r * 34 + 2 * tx]; A1 += red_a[r * 34 + 2 * tx + 1];
    }
    float g0 = A0 / S0, g1 = A1 / S1;
    g0 = 1.0f / (1.0f + expf(-g0));
    g1 = 1.0f / (1.0f + expf(-g1));
    float2 gg; gg.x = g0; gg.y = g1;
    float* op = XC + (size_t)(b * LDIM) * H2 + H + hs + 2 * tx;
    #pragma unroll
    for (int i = 0; i < 8; ++i)
        *(float2*)(op + (size_t)(ty * 8 + i) * H2) = gg;
}

__device__ void run_stage(const NetArgs& a, int s, int bid, int tid, float* lds)
{
    if (s == 0) {
        // fv0 (256 tiles, K=512)  ||  W_sa = W_attn @ W_ue (128 tiles, NN, K=256)
        for (int u = bid; u < 384; u += NBLK) {
            if (u < 256)
                tile32(a.feat, NINP, a.W_inp, NINP, 0, a.b_inp, nullptr,
                       a.fvA, nullptr, H, NINP, (u >> 3) << 5, (u & 7) << 5, tid, lds);
            else {
                int v = u - 256;   // (256,512): 8 m-tiles x 16 n-tiles
                tile32(a.W_attn, H, a.W_ue, H2, 1, nullptr, nullptr,
                       a.wsa, nullptr, H2, H, (v >> 4) << 5, (v & 15) << 5, tid, lds);
            }
        }
    } else if (s == 1) {
        // A0 -> both halves of CA0  ||  xhid0 -> XC[:, :H]
        for (int u = bid; u < 512; u += NBLK) {
            if (u < 256)
                tile32(a.fvA, H, a.W_fe, H2, 0, nullptr, nullptr,
                       a.ca0, a.ca0 + H, H2, H, (u >> 3) << 5, (u & 7) << 5, tid, lds);
            else {
                int v = u - 256;
                tile32(a.fvA, H, a.W_agg, H, 0, a.b_agg, a.mask,
                       a.xc, nullptr, H2, H, (v >> 3) << 5, (v & 7) << 5, tid, lds);
            }
        }
    } else {
        const int t  = (s - 2) / 3;
        const int ph = (s - 2) % 3;
        const float* cac = (t & 1) ? a.ca1 : a.ca0;
        float*       can = (t & 1) ? a.ca0 : a.ca1;
        const float* fin = (t & 1) ? a.fvB : a.fvA;   (void)fin;
        float*     fnext = (t & 1) ? a.fvA : a.fvB;

        if (ph == 0) {
            // strips (blocks 0..63): S + softmax + agg  ||  P' (blocks 64..255)
            if (bid < 64) {
                strip_softmax(cac, a.wsa, a.xc, bid, tid, lds);
            } else if (t < 2) {
                for (int u = bid - 64; u < 256; u += 192)
                    tile32(cac, H2, a.W_ue, H2, 0, nullptr, nullptr,
                           can + H, nullptr, H2, H2, (u >> 3) << 5, (u & 7) << 5, tid, lds);
            }
        } else if (ph == 1) {
            // fv_{t+1} = XC @ W_uv.T + b_uv   (256 tiles, K=512)
            tile32(a.xc, H2, a.W_uv, H2, 0, a.b_uv, nullptr,
                   fnext, nullptr, H, H2, (bid >> 3) << 5, (bid & 7) << 5, tid, lds);
        } else {
            if (t < 2) {
                // A_{t+1} -> can[:, :H]  ||  xhid_{t+1} -> XC[:, :H]
                for (int u = bid; u < 512; u += NBLK) {
                    if (u < 256)
                        tile32(fnext, H, a.W_fe, H2, 0, nullptr, nullptr,
                               can, nullptr, H2, H, (u >> 3) << 5, (u & 7) << 5, tid, lds);
                    else {
                        int v = u - 256;
                        tile32(fnext, H, a.W_agg, H, 0, a.b_agg, a.mask,
                               a.xc, nullptr, H2, H, (v >> 3) << 5, (v & 7) << 5, tid, lds);
                    }
                }
            } else {
                // out = fv3 @ W_oup.T + b_oup   (1024x512, 512 tiles, K=256)
                for (int u = bid; u < 512; u += NBLK)
                    tile32(fnext, H, a.W_oup, H, 0, a.b_oup, nullptr,
                           a.out, nullptr, NINP, H, (u >> 4) << 5, (u & 15) << 5, tid, lds);
            }
        }
    }
}

__global__ __launch_bounds__(256) void efgn_net(NetArgs a, int s0, int s1)
{
    __shared__ float lds[5376];
    const int bid = blockIdx.x, tid = threadIdx.x;
    for (int s = s0; s < s1; ++s) {
        run_stage(a, s, bid, tid, lds);
        if (s + 1 < s1) cg::this_grid().sync();
    }
}

extern "C" void kernel_launch(void* const* d_in, const int* in_sizes, int n_in,
                              void* d_out, int out_size, void* d_ws, size_t ws_size,
                              hipStream_t stream)
{
    NetArgs a;
    a.feat   = (const float*)d_in[0];
    a.mask   = (const float*)d_in[1];
    a.W_inp  = (const float*)d_in[2];
    a.b_inp  = (const float*)d_in[3];
    a.W_oup  = (const float*)d_in[4];
    a.b_oup  = (const float*)d_in[5];
    a.W_fe   = (const float*)d_in[6];   // [7] b_fe cancels
    a.W_ue   = (const float*)d_in[8];   // [9] b_ue cancels
    a.W_agg  = (const float*)d_in[10];
    a.b_agg  = (const float*)d_in[11];
    a.W_uv   = (const float*)d_in[12];
    a.b_uv   = (const float*)d_in[13];
    a.W_attn = (const float*)d_in[14];  // [15] b_attn cancels
    a.out    = (float*)d_out;

    float* ws = (float*)d_ws;
    a.fvA = ws;                       ws += MROWS * H;       // fv0 / fv2
    a.fvB = ws;                       ws += MROWS * H;       // fv1 / fv3
    a.ca0 = ws;                       ws += MROWS * H2;      // CA_0 / CA_2
    a.ca1 = ws;                       ws += MROWS * H2;      // CA_1
    a.xc  = ws;                       ws += MROWS * H2;      // [xhid | agg]
    a.wsa = ws;                       ws += H * H2;          // W_attn @ W_ue

    int s0 = 0, s1 = NSTAGE;
    void* params[] = { (void*)&a, (void*)&s0, (void*)&s1 };
    hipError_t e = hipLaunchCooperativeKernel((const void*)efgn_net,
                                              dim3(NBLK), dim3(256),
                                              params, 0, stream);
    if (e != hipSuccess) {
        (void)hipGetLastError();  // clear sticky error, fall back to multi-launch
        for (int s = 0; s < NSTAGE; ++s)
            efgn_net<<<dim3(NBLK), dim3(256), 0, stream>>>(a, s, s + 1);
    }
}